// Round 14
// baseline (234.298 us; speedup 1.0000x reference)
//
#include <hip/hip_runtime.h>
#include <math.h>

#define NN 100000
#define E0 1600000
#define ETOT (E0 + NN)
#define NEG 0.2f

#define NB 512          // dst buckets
#define BS 196          // nodes per bucket (NB*BS >= NN)
#define CHUNK 4096      // edges per k_bin block
#define PPT 16          // pairs per thread
#define MAXP 4096       // max pairs per bucket (mean 3136, sigma 56)

// ---- DPP cross-lane adds (VALU pipe, no LDS latency) -----------------------
template <int CTRL>
__device__ __forceinline__ float dppadd(float v) {
    int t = __builtin_amdgcn_update_dpp(0, __float_as_int(v), CTRL, 0xf, 0xf, true);
    return v + __int_as_float(t);
}
// full 64-lane sum, every lane gets the result
__device__ __forceinline__ float wsum64(float v) {
    v = dppadd<0xB1>(v);
    v = dppadd<0x4E>(v);
    v = dppadd<0x141>(v);
    v = dppadd<0x140>(v);
    v += __shfl_xor(v, 16);
    v += __shfl_xor(v, 32);
    return v;
}
__device__ __forceinline__ unsigned f2bf_rn(float f) {
    unsigned u = __float_as_uint(f);
    return (u + 0x7FFFu + ((u >> 16) & 1u)) >> 16;
}

// ---- pass A: bucket histogram (LDS-aggregated) -----------------------------
__global__ void k_bhist(const int* __restrict__ ei, int* __restrict__ bcnt) {
    __shared__ int h[NB];
    int tid = threadIdx.x;
    for (int i = tid; i < NB; i += 256) h[i] = 0;
    __syncthreads();
    int stride = gridDim.x * 256;
    for (int e = blockIdx.x * 256 + tid; e < E0; e += stride)
        atomicAdd(&h[ei[E0 + e] / BS], 1);
    __syncthreads();
    for (int i = tid; i < NB; i += 256)
        if (h[i]) atomicAdd(&bcnt[i], h[i]);
}

// ---- pass B: scan bucket counts --------------------------------------------
__global__ void k_bscan(const int* __restrict__ bcnt, int* __restrict__ boff,
                        int* __restrict__ srcsBase, int* __restrict__ cursor,
                        int* __restrict__ rs) {
    __shared__ int s[NB];
    int tid = threadIdx.x;
    int v = bcnt[tid];
    s[tid] = v;
    __syncthreads();
    for (int off = 1; off < NB; off <<= 1) {
        int t = (tid >= off) ? s[tid - off] : 0;
        __syncthreads();
        s[tid] += t;
        __syncthreads();
    }
    int excl = s[tid] - v;
    boff[tid] = excl;
    cursor[tid] = excl;
    int n0 = tid * BS;
    if (n0 > NN) n0 = NN;
    srcsBase[tid] = excl + n0;  // + self-loops of all earlier nodes
    if (tid == 0) rs[NN] = ETOT;  // sentinel
}

// ---- pass C: bin edges into bucket-sorted pair array (run-aggregated) ------
__global__ void k_bin(const int* __restrict__ ei, int* __restrict__ cursor,
                      int2* __restrict__ binned) {
    __shared__ int hist[NB];
    __shared__ int basesh[NB];
    int tid = threadIdx.x;
    long long cbase = (long long)blockIdx.x * CHUNK;
    for (int i = tid; i < NB; i += 256) hist[i] = 0;
    __syncthreads();
    int srcv[PPT], dstv[PPT], rank[PPT], bkt[PPT];
#pragma unroll
    for (int k = 0; k < PPT; ++k) {
        long long e = cbase + k * 256 + tid;
        if (e < E0) {
            int s_ = ei[e];
            int d_ = ei[E0 + e];
            int b = d_ / BS;
            rank[k] = atomicAdd(&hist[b], 1);
            srcv[k] = s_;
            dstv[k] = d_;
            bkt[k] = b;
        } else {
            bkt[k] = -1;
        }
    }
    __syncthreads();
    for (int i = tid; i < NB; i += 256)
        if (hist[i] > 0) basesh[i] = atomicAdd(&cursor[i], hist[i]);
    __syncthreads();
#pragma unroll
    for (int k = 0; k < PPT; ++k)
        if (bkt[k] >= 0) {
            int2 p;
            p.x = srcv[k];
            p.y = dstv[k];
            binned[basesh[bkt[k]] + rank[k]] = p;
        }
}

// ---- pass D: per-bucket finalize: row_start + dst-sorted srcs (coalesced) --
__global__ void k_bfin(const int2* __restrict__ binned, const int* __restrict__ bcnt,
                       const int* __restrict__ boff, const int* __restrict__ srcsBase,
                       int* __restrict__ rs, int* __restrict__ srcs) {
    int b = blockIdx.x;
    int n0 = b * BS;
    if (n0 >= NN) return;
    int nd = NN - n0;
    if (nd > BS) nd = BS;
    int cnt = bcnt[b];
    if (cnt > MAXP) cnt = MAXP;  // statistically impossible; safety
    int base = boff[b];
    int sb = srcsBase[b];
    __shared__ int ldsCnt[256];
    __shared__ int scanA[256];
    __shared__ int rowOffE[256];
    __shared__ int stage[MAXP + BS];
    int tid = threadIdx.x;
    ldsCnt[tid] = 0;
    __syncthreads();
    int srcv[PPT], dl_[PPT], rk_[PPT];
#pragma unroll
    for (int k = 0; k < PPT; ++k) {
        int i = k * 256 + tid;
        if (i < cnt) {
            int2 p = binned[base + i];
            int dl = p.y - n0;
            rk_[k] = atomicAdd(&ldsCnt[dl], 1);
            srcv[k] = p.x;
            dl_[k] = dl;
        } else {
            dl_[k] = -1;
        }
    }
    __syncthreads();
    int v = (tid < nd) ? ldsCnt[tid] + 1 : 0;  // +1 self-loop
    scanA[tid] = v;
    __syncthreads();
    for (int off = 1; off < 256; off <<= 1) {
        int t = (tid >= off) ? scanA[tid - off] : 0;
        __syncthreads();
        scanA[tid] += t;
        __syncthreads();
    }
    rowOffE[tid] = scanA[tid] - v;
    __syncthreads();
    if (tid < nd) {
        int e = rowOffE[tid];
        rs[n0 + tid] = sb + e;
        stage[e] = n0 + tid;  // self-loop occupies first slot
    }
    __syncthreads();
#pragma unroll
    for (int k = 0; k < PPT; ++k)
        if (dl_[k] >= 0) stage[rowOffE[dl_[k]] + 1 + rk_[k]] = srcv[k];
    __syncthreads();
    int tot = cnt + nd;
    for (int i = tid; i < tot; i += 256) srcs[sb + i] = stage[i];
}

// ---------------- xr1 = x @ W1r  (N x 64) -----------------------------------
__global__ void k_linr(const float* __restrict__ x, const float* __restrict__ Wr,
                       float* __restrict__ xr1) {
    int t = blockIdx.x * blockDim.x + threadIdx.x;
    if (t >= NN * 16) return;
    int n = t >> 4;
    int j = (t & 15) << 2;
    const float4 xv = *(const float4*)(x + (long long)n * 4);
    float4 a = {0.f, 0.f, 0.f, 0.f};
#pragma unroll
    for (int k = 0; k < 4; ++k) {
        float4 w = *(const float4*)(Wr + k * 64 + j);
        float xk = k == 0 ? xv.x : k == 1 ? xv.y : k == 2 ? xv.z : xv.w;
        a.x += xk * w.x; a.y += xk * w.y;
        a.z += xk * w.z; a.w += xk * w.w;
    }
    *(float4*)(xr1 + (long long)n * 64 + j) = a;
}

// ------ layer 1 gather: lane = (e_i<0..3> bits4-5, sub<0..15> bits0-3) ------
// sub owns channels sub*4..+3 -> wl[4][4]+at[4]+xrd[4] = 24 weight regs.
// 4 edges/iter; head logit = quad DPP reduce; acc in x-space; 1-pass LN.
__global__ void k_gat1(const float* __restrict__ x, const float* __restrict__ Wl,
                       const float* __restrict__ xr1, const float* __restrict__ att,
                       const int* __restrict__ rs, const int* __restrict__ srcs,
                       const float* __restrict__ b, const float* __restrict__ g,
                       const float* __restrict__ be, float* __restrict__ h) {
    int lane = threadIdx.x & 63;
    int wave = (blockIdx.x * blockDim.x + threadIdx.x) >> 6;
    int nwaves = (gridDim.x * blockDim.x) >> 6;
    int sub = lane & 15;
    int e_i = lane >> 4;
    float wl[4][4], at4[4];
#pragma unroll
    for (int k = 0; k < 4; ++k)
#pragma unroll
        for (int j = 0; j < 4; ++j) wl[k][j] = Wl[k * 64 + sub * 4 + j];
#pragma unroll
    for (int j = 0; j < 4; ++j) at4[j] = att[sub * 4 + j];

    for (int n = wave; n < NN; n += nwaves) {
        const float4 xr = *(const float4*)(xr1 + (long long)n * 64 + sub * 4);
        float xrd[4] = {xr.x, xr.y, xr.z, xr.w};
        int beg = rs[n];
        int end = rs[n + 1];
        float a0 = 0.f, a1 = 0.f, a2 = 0.f, a3 = 0.f, den = 0.f;
        for (int base = beg; base < end; base += 4) {
            int slot = base + e_i;
            bool valid = slot < end;
            int s = srcs[valid ? slot : beg];
            const float4 xa = *(const float4*)(x + (long long)s * 4);
            float p = 0.f;
#pragma unroll
            for (int j = 0; j < 4; ++j) {
                float t = xa.x * wl[0][j] + xa.y * wl[1][j] + xa.z * wl[2][j] +
                          xa.w * wl[3][j];
                float u = t + xrd[j];
                u = fmaxf(u, NEG * u);
                p += u * at4[j];
            }
            p = dppadd<0xB1>(p);   // xor1 \ sum the 4 subs of this head
            p = dppadd<0x4E>(p);   // xor2 /  (quad == sub-quad == one head)
            float ex = valid ? __expf(p) : 0.f;
            den += ex;
            a0 += ex * xa.x;
            a1 += ex * xa.y;
            a2 += ex * xa.z;
            a3 += ex * xa.w;
        }
        // reduce over e_i (lane bits 4,5)
#pragma unroll
        for (int m = 16; m <= 32; m <<= 1) {
            a0 += __shfl_xor(a0, m);
            a1 += __shfl_xor(a1, m);
            a2 += __shfl_xor(a2, m);
            a3 += __shfl_xor(a3, m);
            den += __shfl_xor(den, m);
        }
        // cf bijection; head(cf) == sub>>2 matches this lane's den
        int cf = (sub >> 2) * 16 + (sub & 3) * 4 + e_i;
        float v = (a0 * Wl[cf] + a1 * Wl[64 + cf] + a2 * Wl[128 + cf] +
                   a3 * Wl[192 + cf]) / den + b[cf];
        // single-pass LN: parallel Sum(v), Sum(v^2) chains
        float s1 = wsum64(v);
        float s2 = wsum64(v * v);
        float mu = s1 * (1.f / 64.f);
        float var = fmaxf(s2 * (1.f / 64.f) - mu * mu, 0.f);
        float y = (v - mu) * rsqrtf(var + 1e-5f) * g[cf] + be[cf];
        h[(long long)n * 64 + cf] = y > 0.f ? y : expm1f(y);
    }
}

// ---- layer 2 node transform: h[N,64] @ W[64,32]; xl2 packed bf16 -----------
__global__ void k_lin2(const float* __restrict__ h, const float* __restrict__ Wl,
                       const float* __restrict__ Wr, unsigned* __restrict__ xl2p,
                       float* __restrict__ xr2) {
    __shared__ float wl_s[2048];
    __shared__ float wr_s[2048];
    for (int i = threadIdx.x; i < 2048; i += blockDim.x) {
        wl_s[i] = Wl[i];
        wr_s[i] = Wr[i];
    }
    __syncthreads();
    int t = blockIdx.x * blockDim.x + threadIdx.x;
    if (t >= NN * 16) return;
    int n = t >> 4, j2 = t & 15;
    const float* hr = h + (long long)n * 64;
    float al0 = 0.f, al1 = 0.f, ar0 = 0.f, ar1 = 0.f;
#pragma unroll 8
    for (int k = 0; k < 64; ++k) {
        float hv = hr[k];
        al0 += hv * wl_s[k * 32 + j2 * 2];
        al1 += hv * wl_s[k * 32 + j2 * 2 + 1];
        ar0 += hv * wr_s[k * 32 + j2 * 2];
        ar1 += hv * wr_s[k * 32 + j2 * 2 + 1];
    }
    xl2p[(long long)n * 16 + j2] = (f2bf_rn(al1) << 16) | f2bf_rn(al0);
    *(float2*)(xr2 + (long long)n * 32 + j2 * 2) = {ar0, ar1};
}

// ------ layer 2 gather: lane = (e_i<0..7>, cg<0..7>); 8 edges/iter ----------
// gathers 8B (4 bf16 channels) per lane from packed xl2. (R13 best)
__global__ void k_gat2(const unsigned* __restrict__ xl2p,
                       const float* __restrict__ xr2,
                       const float* __restrict__ att, const int* __restrict__ rs,
                       const int* __restrict__ srcs, const float* __restrict__ b,
                       const float* __restrict__ g, const float* __restrict__ be,
                       float* __restrict__ out) {
    int lane = threadIdx.x & 63;
    int wave = (blockIdx.x * blockDim.x + threadIdx.x) >> 6;
    int nwaves = (gridDim.x * blockDim.x) >> 6;
    int e_i = lane >> 3;
    int cg = lane & 7;
    float at[4];
#pragma unroll
    for (int j = 0; j < 4; ++j) at[j] = att[cg * 4 + j];

    for (int n = wave; n < NN; n += nwaves) {
        const float4 xr4 = *(const float4*)(xr2 + (long long)n * 32 + cg * 4);
        float xrd[4] = {xr4.x, xr4.y, xr4.z, xr4.w};
        int beg = rs[n];
        int end = rs[n + 1];
        float acc[4] = {0.f, 0.f, 0.f, 0.f};
        float den = 0.f;
        int slot = beg + e_i;
        bool valid = slot < end;
        int s = srcs[valid ? slot : beg];
        uint2 xp = *(const uint2*)(xl2p + (long long)s * 16 + cg * 2);
        for (int base = beg; base < end; base += 8) {
            int nslot = base + 8 + e_i;
            bool nvalid = nslot < end;
            int ns = srcs[nvalid ? nslot : beg];
            uint2 xq = *(const uint2*)(xl2p + (long long)ns * 16 + cg * 2);
            float xv0 = __uint_as_float(xp.x << 16);
            float xv1 = __uint_as_float(xp.x & 0xFFFF0000u);
            float xv2 = __uint_as_float(xp.y << 16);
            float xv3 = __uint_as_float(xp.y & 0xFFFF0000u);
            float u0 = xv0 + xrd[0], u1 = xv1 + xrd[1];
            float u2 = xv2 + xrd[2], u3 = xv3 + xrd[3];
            u0 = fmaxf(u0, NEG * u0);
            u1 = fmaxf(u1, NEG * u1);
            u2 = fmaxf(u2, NEG * u2);
            u3 = fmaxf(u3, NEG * u3);
            float p = u0 * at[0] + u1 * at[1] + u2 * at[2] + u3 * at[3];
            p = dppadd<0xB1>(p);                 // xor1
            p = dppadd<0x4E>(p);                 // xor2 -> quad sums
            p = dppadd<0x141>(p);                // cross-quad -> 8-group sum
            float ex = valid ? __expf(p) : 0.f;
            den += ex;
            acc[0] += ex * xv0;
            acc[1] += ex * xv1;
            acc[2] += ex * xv2;
            acc[3] += ex * xv3;
            xp = xq;
            valid = nvalid;
        }
#pragma unroll
        for (int m = 8; m <= 32; m <<= 1) {
#pragma unroll
            for (int j = 0; j < 4; ++j) acc[j] += __shfl_xor(acc[j], m);
            den += __shfl_xor(den, m);
        }
        int e3 = e_i & 3;
        float v = acc[0];
#pragma unroll
        for (int j = 1; j < 4; ++j) v = (e3 == j) ? acc[j] : v;
        int cf = cg * 4 + e3;
        v = v / den + b[cf];
        float mu = wsum64(v) * (1.f / 64.f);
        float cc = v - mu;
        float var = wsum64(cc * cc) * (1.f / 64.f);
        float y = cc * rsqrtf(var + 1e-5f) * g[cf] + be[cf];
        if (e_i < 4) out[(long long)n * 32 + cf] = y;
    }
}

extern "C" void kernel_launch(void* const* d_in, const int* in_sizes, int n_in,
                              void* d_out, int out_size, void* d_ws, size_t ws_size,
                              hipStream_t stream) {
    const float* x   = (const float*)d_in[0];
    const int*   ei  = (const int*)d_in[1];
    const float* W1l = (const float*)d_in[2];
    const float* W1r = (const float*)d_in[3];
    const float* a1  = (const float*)d_in[4];
    const float* b1  = (const float*)d_in[5];
    const float* g1  = (const float*)d_in[6];
    const float* be1 = (const float*)d_in[7];
    const float* W2l = (const float*)d_in[8];
    const float* W2r = (const float*)d_in[9];
    const float* a2  = (const float*)d_in[10];
    const float* b2  = (const float*)d_in[11];
    const float* g2  = (const float*)d_in[12];
    const float* be2 = (const float*)d_in[13];
    float* out = (float*)d_out;

    float* ws = (float*)d_ws;
    float* h   = ws;             // N*64 (layer-1 out; written after CSR done)
    float* xr1 = ws + 6400000;   // N*64 (dead after k_gat1)
    unsigned* xl2p = (unsigned*)(ws + 6400000);  // N*16 uints (reuses xr1)
    float* xr2 = ws + 9600000;   // N*32
    int2* binned = (int2*)ws;    // E0 pairs = 12.8 MB, aliases h (CSR phase only)
    int* ib        = (int*)(ws + 12800000);
    int* rs        = ib;              // NN+1 (sentinel)
    int* srcs      = ib + 100001;     // ETOT
    int* bcnt      = ib + 1800100;    // NB
    int* boff      = ib + 1800100 + NB;
    int* srcsBase  = ib + 1800100 + 2 * NB;
    int* cursor    = ib + 1800100 + 3 * NB;

    // ---- CSR build via 2-level counting sort ----
    hipMemsetAsync(bcnt, 0, NB * sizeof(int), stream);
    k_bhist<<<256, 256, 0, stream>>>(ei, bcnt);
    k_bscan<<<1, NB, 0, stream>>>(bcnt, boff, srcsBase, cursor, rs);
    k_bin<<<(E0 + CHUNK - 1) / CHUNK, 256, 0, stream>>>(ei, cursor, binned);
    k_bfin<<<NB, 256, 0, stream>>>(binned, bcnt, boff, srcsBase, rs, srcs);
    // xr1 precompute (independent of CSR order)
    k_linr<<<(NN * 16 + 255) / 256, 256, 0, stream>>>(x, W1r, xr1);

    // ---- layer 1 ----
    k_gat1<<<2048, 256, 0, stream>>>(x, W1l, xr1, a1, rs, srcs, b1, g1, be1, h);
    // ---- layer 2 ----
    k_lin2<<<(NN * 16 + 255) / 256, 256, 0, stream>>>(h, W2l, W2r, xl2p, xr2);
    k_gat2<<<2048, 256, 0, stream>>>(xl2p, xr2, a2, rs, srcs, b2, g2, be2, out);
}

// Round 15
// 221.546 us; speedup vs baseline: 1.0576x; 1.0576x over previous
//
#include <hip/hip_runtime.h>
#include <math.h>

#define NN 100000
#define E0 1600000
#define ETOT (E0 + NN)
#define NEG 0.2f

#define NB 512          // dst buckets
#define BS 196          // nodes per bucket (NB*BS >= NN)
#define CHUNK 4096      // edges per k_bin block
#define PPT 16          // pairs per thread
#define MAXP 4096       // max pairs per bucket (mean 3136, sigma 56)

// ---- DPP cross-lane adds (VALU pipe, no LDS latency) -----------------------
template <int CTRL>
__device__ __forceinline__ float dppadd(float v) {
    int t = __builtin_amdgcn_update_dpp(0, __float_as_int(v), CTRL, 0xf, 0xf, true);
    return v + __int_as_float(t);
}
// full 64-lane sum, every lane gets the result
__device__ __forceinline__ float wsum64(float v) {
    v = dppadd<0xB1>(v);
    v = dppadd<0x4E>(v);
    v = dppadd<0x141>(v);
    v = dppadd<0x140>(v);
    v += __shfl_xor(v, 16);
    v += __shfl_xor(v, 32);
    return v;
}
__device__ __forceinline__ unsigned f2bf_rn(float f) {
    unsigned u = __float_as_uint(f);
    return (u + 0x7FFFu + ((u >> 16) & 1u)) >> 16;
}

// ---- pass A: bucket histogram (LDS-aggregated) -----------------------------
__global__ void k_bhist(const int* __restrict__ ei, int* __restrict__ bcnt) {
    __shared__ int h[NB];
    int tid = threadIdx.x;
    for (int i = tid; i < NB; i += 256) h[i] = 0;
    __syncthreads();
    int stride = gridDim.x * 256;
    for (int e = blockIdx.x * 256 + tid; e < E0; e += stride)
        atomicAdd(&h[ei[E0 + e] / BS], 1);
    __syncthreads();
    for (int i = tid; i < NB; i += 256)
        if (h[i]) atomicAdd(&bcnt[i], h[i]);
}

// ---- pass B: scan bucket counts --------------------------------------------
__global__ void k_bscan(const int* __restrict__ bcnt, int* __restrict__ boff,
                        int* __restrict__ srcsBase, int* __restrict__ cursor,
                        int* __restrict__ rs) {
    __shared__ int s[NB];
    int tid = threadIdx.x;
    int v = bcnt[tid];
    s[tid] = v;
    __syncthreads();
    for (int off = 1; off < NB; off <<= 1) {
        int t = (tid >= off) ? s[tid - off] : 0;
        __syncthreads();
        s[tid] += t;
        __syncthreads();
    }
    int excl = s[tid] - v;
    boff[tid] = excl;
    cursor[tid] = excl;
    int n0 = tid * BS;
    if (n0 > NN) n0 = NN;
    srcsBase[tid] = excl + n0;  // + self-loops of all earlier nodes
    if (tid == 0) rs[NN] = ETOT;  // sentinel
}

// ---- pass C: bin edges into bucket-sorted pair array (run-aggregated) ------
__global__ void k_bin(const int* __restrict__ ei, int* __restrict__ cursor,
                      int2* __restrict__ binned) {
    __shared__ int hist[NB];
    __shared__ int basesh[NB];
    int tid = threadIdx.x;
    long long cbase = (long long)blockIdx.x * CHUNK;
    for (int i = tid; i < NB; i += 256) hist[i] = 0;
    __syncthreads();
    int srcv[PPT], dstv[PPT], rank[PPT], bkt[PPT];
#pragma unroll
    for (int k = 0; k < PPT; ++k) {
        long long e = cbase + k * 256 + tid;
        if (e < E0) {
            int s_ = ei[e];
            int d_ = ei[E0 + e];
            int b = d_ / BS;
            rank[k] = atomicAdd(&hist[b], 1);
            srcv[k] = s_;
            dstv[k] = d_;
            bkt[k] = b;
        } else {
            bkt[k] = -1;
        }
    }
    __syncthreads();
    for (int i = tid; i < NB; i += 256)
        if (hist[i] > 0) basesh[i] = atomicAdd(&cursor[i], hist[i]);
    __syncthreads();
#pragma unroll
    for (int k = 0; k < PPT; ++k)
        if (bkt[k] >= 0) {
            int2 p;
            p.x = srcv[k];
            p.y = dstv[k];
            binned[basesh[bkt[k]] + rank[k]] = p;
        }
}

// ---- pass D: per-bucket finalize: row_start + dst-sorted srcs (coalesced) --
__global__ void k_bfin(const int2* __restrict__ binned, const int* __restrict__ bcnt,
                       const int* __restrict__ boff, const int* __restrict__ srcsBase,
                       int* __restrict__ rs, int* __restrict__ srcs) {
    int b = blockIdx.x;
    int n0 = b * BS;
    if (n0 >= NN) return;
    int nd = NN - n0;
    if (nd > BS) nd = BS;
    int cnt = bcnt[b];
    if (cnt > MAXP) cnt = MAXP;  // statistically impossible; safety
    int base = boff[b];
    int sb = srcsBase[b];
    __shared__ int ldsCnt[256];
    __shared__ int scanA[256];
    __shared__ int rowOffE[256];
    __shared__ int stage[MAXP + BS];
    int tid = threadIdx.x;
    ldsCnt[tid] = 0;
    __syncthreads();
    int srcv[PPT], dl_[PPT], rk_[PPT];
#pragma unroll
    for (int k = 0; k < PPT; ++k) {
        int i = k * 256 + tid;
        if (i < cnt) {
            int2 p = binned[base + i];
            int dl = p.y - n0;
            rk_[k] = atomicAdd(&ldsCnt[dl], 1);
            srcv[k] = p.x;
            dl_[k] = dl;
        } else {
            dl_[k] = -1;
        }
    }
    __syncthreads();
    int v = (tid < nd) ? ldsCnt[tid] + 1 : 0;  // +1 self-loop
    scanA[tid] = v;
    __syncthreads();
    for (int off = 1; off < 256; off <<= 1) {
        int t = (tid >= off) ? scanA[tid - off] : 0;
        __syncthreads();
        scanA[tid] += t;
        __syncthreads();
    }
    rowOffE[tid] = scanA[tid] - v;
    __syncthreads();
    if (tid < nd) {
        int e = rowOffE[tid];
        rs[n0 + tid] = sb + e;
        stage[e] = n0 + tid;  // self-loop occupies first slot
    }
    __syncthreads();
#pragma unroll
    for (int k = 0; k < PPT; ++k)
        if (dl_[k] >= 0) stage[rowOffE[dl_[k]] + 1 + rk_[k]] = srcv[k];
    __syncthreads();
    int tot = cnt + nd;
    for (int i = tid; i < tot; i += 256) srcs[sb + i] = stage[i];
}

// ---------------- xr1 = x @ W1r  (N x 64) -----------------------------------
__global__ void k_linr(const float* __restrict__ x, const float* __restrict__ Wr,
                       float* __restrict__ xr1) {
    int t = blockIdx.x * blockDim.x + threadIdx.x;
    if (t >= NN * 16) return;
    int n = t >> 4;
    int j = (t & 15) << 2;
    const float4 xv = *(const float4*)(x + (long long)n * 4);
    float4 a = {0.f, 0.f, 0.f, 0.f};
#pragma unroll
    for (int k = 0; k < 4; ++k) {
        float4 w = *(const float4*)(Wr + k * 64 + j);
        float xk = k == 0 ? xv.x : k == 1 ? xv.y : k == 2 ? xv.z : xv.w;
        a.x += xk * w.x; a.y += xk * w.y;
        a.z += xk * w.z; a.w += xk * w.w;
    }
    *(float4*)(xr1 + (long long)n * 64 + j) = a;
}

// ------ layer 1 gather: lane = (e_i<0..7>, sub<0..7>); 8 edges/iter ---------
// xr from precomputed xr1 (frees wr's 32 regs); launch_bounds caps at 5 w/SIMD.
__global__ __launch_bounds__(256, 5) void k_gat1(
        const float* __restrict__ x, const float* __restrict__ Wl,
        const float* __restrict__ xr1, const float* __restrict__ att,
        const int* __restrict__ rs, const int* __restrict__ srcs,
        const float* __restrict__ b, const float* __restrict__ g,
        const float* __restrict__ be, float* __restrict__ h) {
    int lane = threadIdx.x & 63;
    int wave = (blockIdx.x * blockDim.x + threadIdx.x) >> 6;
    int nwaves = (gridDim.x * blockDim.x) >> 6;
    int e_i = lane >> 3;
    int sub = lane & 7;
    float wl[4][8], at[8];
#pragma unroll
    for (int k = 0; k < 4; ++k)
#pragma unroll
        for (int j = 0; j < 8; ++j) wl[k][j] = Wl[k * 64 + sub * 8 + j];
#pragma unroll
    for (int j = 0; j < 8; ++j) at[j] = att[sub * 8 + j];

    for (int n = wave; n < NN; n += nwaves) {
        const float4 r0 = *(const float4*)(xr1 + (long long)n * 64 + sub * 8);
        const float4 r1 = *(const float4*)(xr1 + (long long)n * 64 + sub * 8 + 4);
        float xrd[8] = {r0.x, r0.y, r0.z, r0.w, r1.x, r1.y, r1.z, r1.w};
        int beg = rs[n];
        int end = rs[n + 1];
        float acc4[4] = {0.f, 0.f, 0.f, 0.f};
        float den = 0.f;
        int slot = beg + e_i;
        bool valid = slot < end;
        int s = srcs[valid ? slot : beg];
        float4 xa = *(const float4*)(x + (long long)s * 4);
        for (int base = beg; base < end; base += 8) {
            int nslot = base + 8 + e_i;
            bool nvalid = nslot < end;
            int ns = srcs[nvalid ? nslot : beg];
            float4 xn = *(const float4*)(x + (long long)ns * 4);
            float p = 0.f;
#pragma unroll
            for (int j = 0; j < 8; ++j) {
                float t = xa.x * wl[0][j] + xa.y * wl[1][j] + xa.z * wl[2][j] +
                          xa.w * wl[3][j];
                float u = t + xrd[j];
                u = fmaxf(u, NEG * u);
                p += u * at[j];
            }
            p = dppadd<0xB1>(p);                 // xor1: pair of subs = one head
            float ex = valid ? __expf(p) : 0.f;
            den += ex;
            acc4[0] += ex * xa.x;
            acc4[1] += ex * xa.y;
            acc4[2] += ex * xa.z;
            acc4[3] += ex * xa.w;
            xa = xn;
            valid = nvalid;
        }
#pragma unroll
        for (int m = 8; m <= 32; m <<= 1) {
#pragma unroll
            for (int k = 0; k < 4; ++k) acc4[k] += __shfl_xor(acc4[k], m);
            den += __shfl_xor(den, m);
        }
        int cf = sub * 8 + e_i;  // bijection over 0..63, same head as den
        float v = (acc4[0] * Wl[cf] + acc4[1] * Wl[64 + cf] +
                   acc4[2] * Wl[128 + cf] + acc4[3] * Wl[192 + cf]) / den + b[cf];
        // single-pass LN: Sum(v) and Sum(v^2) reduced in parallel chains
        float s1 = wsum64(v);
        float s2 = wsum64(v * v);
        float mu = s1 * (1.f / 64.f);
        float var = fmaxf(s2 * (1.f / 64.f) - mu * mu, 0.f);
        float y = (v - mu) * rsqrtf(var + 1e-5f) * g[cf] + be[cf];
        h[(long long)n * 64 + cf] = y > 0.f ? y : expm1f(y);
    }
}

// ---- layer 2 node transform: h[N,64] @ W[64,32]; xl2 packed bf16 -----------
__global__ void k_lin2(const float* __restrict__ h, const float* __restrict__ Wl,
                       const float* __restrict__ Wr, unsigned* __restrict__ xl2p,
                       float* __restrict__ xr2) {
    __shared__ float wl_s[2048];
    __shared__ float wr_s[2048];
    for (int i = threadIdx.x; i < 2048; i += blockDim.x) {
        wl_s[i] = Wl[i];
        wr_s[i] = Wr[i];
    }
    __syncthreads();
    int t = blockIdx.x * blockDim.x + threadIdx.x;
    if (t >= NN * 16) return;
    int n = t >> 4, j2 = t & 15;
    const float* hr = h + (long long)n * 64;
    float al0 = 0.f, al1 = 0.f, ar0 = 0.f, ar1 = 0.f;
#pragma unroll 8
    for (int k = 0; k < 64; ++k) {
        float hv = hr[k];
        al0 += hv * wl_s[k * 32 + j2 * 2];
        al1 += hv * wl_s[k * 32 + j2 * 2 + 1];
        ar0 += hv * wr_s[k * 32 + j2 * 2];
        ar1 += hv * wr_s[k * 32 + j2 * 2 + 1];
    }
    xl2p[(long long)n * 16 + j2] = (f2bf_rn(al1) << 16) | f2bf_rn(al0);
    *(float2*)(xr2 + (long long)n * 32 + j2 * 2) = {ar0, ar1};
}

// ------ layer 2 gather: lane = (e_i<0..7>, cg<0..7>); 8 edges/iter ----------
// gathers 8B (4 bf16 channels) per lane from packed xl2. (R13 best)
__global__ void k_gat2(const unsigned* __restrict__ xl2p,
                       const float* __restrict__ xr2,
                       const float* __restrict__ att, const int* __restrict__ rs,
                       const int* __restrict__ srcs, const float* __restrict__ b,
                       const float* __restrict__ g, const float* __restrict__ be,
                       float* __restrict__ out) {
    int lane = threadIdx.x & 63;
    int wave = (blockIdx.x * blockDim.x + threadIdx.x) >> 6;
    int nwaves = (gridDim.x * blockDim.x) >> 6;
    int e_i = lane >> 3;
    int cg = lane & 7;
    float at[4];
#pragma unroll
    for (int j = 0; j < 4; ++j) at[j] = att[cg * 4 + j];

    for (int n = wave; n < NN; n += nwaves) {
        const float4 xr4 = *(const float4*)(xr2 + (long long)n * 32 + cg * 4);
        float xrd[4] = {xr4.x, xr4.y, xr4.z, xr4.w};
        int beg = rs[n];
        int end = rs[n + 1];
        float acc[4] = {0.f, 0.f, 0.f, 0.f};
        float den = 0.f;
        int slot = beg + e_i;
        bool valid = slot < end;
        int s = srcs[valid ? slot : beg];
        uint2 xp = *(const uint2*)(xl2p + (long long)s * 16 + cg * 2);
        for (int base = beg; base < end; base += 8) {
            int nslot = base + 8 + e_i;
            bool nvalid = nslot < end;
            int ns = srcs[nvalid ? nslot : beg];
            uint2 xq = *(const uint2*)(xl2p + (long long)ns * 16 + cg * 2);
            float xv0 = __uint_as_float(xp.x << 16);
            float xv1 = __uint_as_float(xp.x & 0xFFFF0000u);
            float xv2 = __uint_as_float(xp.y << 16);
            float xv3 = __uint_as_float(xp.y & 0xFFFF0000u);
            float u0 = xv0 + xrd[0], u1 = xv1 + xrd[1];
            float u2 = xv2 + xrd[2], u3 = xv3 + xrd[3];
            u0 = fmaxf(u0, NEG * u0);
            u1 = fmaxf(u1, NEG * u1);
            u2 = fmaxf(u2, NEG * u2);
            u3 = fmaxf(u3, NEG * u3);
            float p = u0 * at[0] + u1 * at[1] + u2 * at[2] + u3 * at[3];
            p = dppadd<0xB1>(p);                 // xor1
            p = dppadd<0x4E>(p);                 // xor2 -> quad sums
            p = dppadd<0x141>(p);                // cross-quad -> 8-group sum
            float ex = valid ? __expf(p) : 0.f;
            den += ex;
            acc[0] += ex * xv0;
            acc[1] += ex * xv1;
            acc[2] += ex * xv2;
            acc[3] += ex * xv3;
            xp = xq;
            valid = nvalid;
        }
#pragma unroll
        for (int m = 8; m <= 32; m <<= 1) {
#pragma unroll
            for (int j = 0; j < 4; ++j) acc[j] += __shfl_xor(acc[j], m);
            den += __shfl_xor(den, m);
        }
        int e3 = e_i & 3;
        float v = acc[0];
#pragma unroll
        for (int j = 1; j < 4; ++j) v = (e3 == j) ? acc[j] : v;
        int cf = cg * 4 + e3;
        v = v / den + b[cf];
        float mu = wsum64(v) * (1.f / 64.f);
        float cc = v - mu;
        float var = wsum64(cc * cc) * (1.f / 64.f);
        float y = cc * rsqrtf(var + 1e-5f) * g[cf] + be[cf];
        if (e_i < 4) out[(long long)n * 32 + cf] = y;
    }
}

extern "C" void kernel_launch(void* const* d_in, const int* in_sizes, int n_in,
                              void* d_out, int out_size, void* d_ws, size_t ws_size,
                              hipStream_t stream) {
    const float* x   = (const float*)d_in[0];
    const int*   ei  = (const int*)d_in[1];
    const float* W1l = (const float*)d_in[2];
    const float* W1r = (const float*)d_in[3];
    const float* a1  = (const float*)d_in[4];
    const float* b1  = (const float*)d_in[5];
    const float* g1  = (const float*)d_in[6];
    const float* be1 = (const float*)d_in[7];
    const float* W2l = (const float*)d_in[8];
    const float* W2r = (const float*)d_in[9];
    const float* a2  = (const float*)d_in[10];
    const float* b2  = (const float*)d_in[11];
    const float* g2  = (const float*)d_in[12];
    const float* be2 = (const float*)d_in[13];
    float* out = (float*)d_out;

    float* ws = (float*)d_ws;
    float* h   = ws;             // N*64 (layer-1 out; written after CSR done)
    float* xr1 = ws + 6400000;   // N*64 (dead after k_gat1)
    unsigned* xl2p = (unsigned*)(ws + 6400000);  // N*16 uints (reuses xr1)
    float* xr2 = ws + 9600000;   // N*32
    int2* binned = (int2*)ws;    // E0 pairs = 12.8 MB, aliases h (CSR phase only)
    int* ib        = (int*)(ws + 12800000);
    int* rs        = ib;              // NN+1 (sentinel)
    int* srcs      = ib + 100001;     // ETOT
    int* bcnt      = ib + 1800100;    // NB
    int* boff      = ib + 1800100 + NB;
    int* srcsBase  = ib + 1800100 + 2 * NB;
    int* cursor    = ib + 1800100 + 3 * NB;

    // ---- CSR build via 2-level counting sort ----
    hipMemsetAsync(bcnt, 0, NB * sizeof(int), stream);
    k_bhist<<<256, 256, 0, stream>>>(ei, bcnt);
    k_bscan<<<1, NB, 0, stream>>>(bcnt, boff, srcsBase, cursor, rs);
    k_bin<<<(E0 + CHUNK - 1) / CHUNK, 256, 0, stream>>>(ei, cursor, binned);
    k_bfin<<<NB, 256, 0, stream>>>(binned, bcnt, boff, srcsBase, rs, srcs);
    // xr1 precompute (independent of CSR order; binned region is separate)
    k_linr<<<(NN * 16 + 255) / 256, 256, 0, stream>>>(x, W1r, xr1);

    // ---- layer 1 ----
    k_gat1<<<2048, 256, 0, stream>>>(x, W1l, xr1, a1, rs, srcs, b1, g1, be1, h);
    // ---- layer 2 ----
    k_lin2<<<(NN * 16 + 255) / 256, 256, 0, stream>>>(h, W2l, W2r, xl2p, xr2);
    k_gat2<<<2048, 256, 0, stream>>>(xl2p, xr2, a2, rs, srcs, b2, g2, be2, out);
}